// Round 8
// baseline (187.549 us; speedup 1.0000x reference)
//
#include <hip/hip_runtime.h>

typedef unsigned short u16;
typedef unsigned int   u32;
typedef __bf16 bf16x8 __attribute__((ext_vector_type(8)));
typedef float  f32x4  __attribute__((ext_vector_type(4)));

#define DEVI __device__ __forceinline__

DEVI u16 f2bf(float f) {
    union { float f; u32 u; } c; c.f = f;
    u32 u = c.u;
    u32 r = (u + 0x7fffu + ((u >> 16) & 1u)) >> 16;
    return (u16)r;
}
DEVI float bf2f(u16 v) {
    union { u32 u; float f; } c; c.u = ((u32)v) << 16;
    return c.f;
}

DEVI void gload16(const void* g, void* l) {
    __builtin_amdgcn_global_load_lds(
        (const __attribute__((address_space(1))) void*)g,
        (__attribute__((address_space(3))) void*)l, 16, 0, 0);
}

// ---------------- 256x256 m201-style 8-phase GEMM ----------------
// LDS (u16 units): buffer q at q*32768. Slots (16KB each, [256 rows][32 cols],
// 64B row stride, chunk swizzle: physical chunk p holds logical p^(row&3)):
//   A0 @+0, A1 @+8192, B0 @+16384, B1 @+24576.
// K-tile (BK=64) = 4 phases (m-pairs i=0..3). First phase reads B for the
// WHOLE tile into registers (8 b128, held 4 phases) + A-pair (4); later
// phases read only A (4). Phase: reads -> stage -> BAR -> lgkmcnt(0)+
// sched_barrier -> setprio1 + 16 MFMA + setprio0 -> [vmcnt gate] -> BAR.
// vmcnt gates only at p3/p7 (before the closing barrier: vmcnt is per-wave,
// the barrier globalizes completion). Stage rotation gives 4-7 phase
// stage->consume gaps (>= HBM latency).

#define VMW(N)  asm volatile("s_waitcnt vmcnt(" #N ")" ::: "memory")
#define BAR     __builtin_amdgcn_s_barrier()
#define SP1     __builtin_amdgcn_s_setprio(1)
#define SP0     __builtin_amdgcn_s_setprio(0)
#define SCB     __builtin_amdgcn_sched_barrier(0)
#define LGKM0   asm volatile("s_waitcnt lgkmcnt(0)" ::: "memory")
#define LGKM8   asm volatile("s_waitcnt lgkmcnt(8)" ::: "memory")

// stage one 16KB slot (256 rows x 32 cols bf16): 2 x 16B per thread
DEVI void stage_kh(const u16* g, u16* slot, int tid) {
    const int wvb = (tid >> 6) << 9;             // wave base (u16), dest linear
    const int r = tid >> 2;                      // row 0..127 (and +128)
    const int p = tid & 3;
    const int c = p ^ (r & 3);                   // pre-swizzled source chunk
    const long off = (long)r * 1024 + (c << 3);
    gload16(g + off, slot + wvb);
    gload16(g + off + (long)128 * 1024, slot + 4096 + wvb);
}

DEVI f32x4 mfma(const bf16x8& a, const bf16x8& b, const f32x4& c) {
    return __builtin_amdgcn_mfma_f32_16x16x32_bf16(a, b, c, 0, 0, 0);
}

// One phase. I = m-pair (0..3), Q = buffer base (u16). Stages/gate inline.
#define PHASE(I, Q, STAGE_CODE, GATE_CODE)                                   \
    {                                                                        \
        if (I == 0) {                                                        \
            _Pragma("unroll")                                                \
            for (int nf = 0; nf < 4; ++nf) {                                 \
                bh[nf][0] = *(const bf16x8*)(lds + (Q) + 16384 + nf * 512 + bbase); \
                bh[nf][1] = *(const bf16x8*)(lds + (Q) + 24576 + nf * 512 + bbase); \
            }                                                                \
        }                                                                    \
        a00 = *(const bf16x8*)(lds + (Q) + (I) * 1024 + abase);              \
        a01 = *(const bf16x8*)(lds + (Q) + 8192 + (I) * 1024 + abase);       \
        a10 = *(const bf16x8*)(lds + (Q) + (I) * 1024 + 512 + abase);        \
        a11 = *(const bf16x8*)(lds + (Q) + 8192 + (I) * 1024 + 512 + abase); \
        if (I == 0) { LGKM8; }                                               \
        STAGE_CODE;                                                          \
        SCB; BAR;                                                            \
        LGKM0; SCB;                                                          \
        SP1;                                                                 \
        _Pragma("unroll")                                                    \
        for (int nf = 0; nf < 4; ++nf) {                                     \
            acc[(I) * 2][nf]     = mfma(a00, bh[nf][0], acc[(I) * 2][nf]);   \
            acc[(I) * 2][nf]     = mfma(a01, bh[nf][1], acc[(I) * 2][nf]);   \
            acc[(I) * 2 + 1][nf] = mfma(a10, bh[nf][0], acc[(I) * 2 + 1][nf]); \
            acc[(I) * 2 + 1][nf] = mfma(a11, bh[nf][1], acc[(I) * 2 + 1][nf]); \
        }                                                                    \
        SP0;                                                                 \
        GATE_CODE;                                                           \
        BAR;                                                                 \
    }

#define NOSTAGE do {} while (0)
#define NOGATE  do {} while (0)

DEVI void pipe256(const u16* Ab, const u16* Bb, u16* lds,
                  f32x4 (&acc)[8][4], int tid) {
    const int lane = tid & 63;
    const int wm = (tid >> 6) >> 2, wn = (tid >> 6) & 3;
    const int pch = ((lane >> 4) ^ (lane & 3)) << 3;
    const int abase = (wm * 128 + (lane & 15)) * 32 + pch;   // slot-relative
    const int bbase = (wn * 64 + (lane & 15)) * 32 + pch;    // slot-relative

    // prologue: T0.{B,A} -> b0, T1.B -> b1.B   (12 loads)
    stage_kh(Bb,      lds + 16384, tid);
    stage_kh(Bb + 32, lds + 24576, tid);
    stage_kh(Ab,      lds + 0,     tid);
    stage_kh(Ab + 32, lds + 8192,  tid);
    stage_kh(Bb + 64, lds + 49152, tid);
    stage_kh(Bb + 96, lds + 57344, tid);
    VMW(4); BAR;                             // T0 landed; T1.B in flight

    bf16x8 bh[4][2];
    bf16x8 a00, a01, a10, a11;

#pragma unroll 1
    for (int j = 0; j < 7; ++j) {
        const u16* A1g = Ab + (2 * j + 1) * 64;
        const u16* A2g = Ab + (2 * j + 2) * 64;
        const u16* B2g = Bb + (2 * j + 2) * 64;
        const u16* B3g = Bb + (2 * j + 3) * 64;
        // tile T0 = 2j in buffer 0
        PHASE(0, 0,
              { stage_kh(A1g, lds + 32768, tid); stage_kh(A1g + 32, lds + 40960, tid); },
              NOGATE);
        PHASE(1, 0,
              { stage_kh(B2g, lds + 16384, tid); stage_kh(B2g + 32, lds + 24576, tid); },
              NOGATE);
        PHASE(2, 0, NOSTAGE, NOGATE);
        PHASE(3, 0, NOSTAGE, VMW(4));
        // tile T1 = 2j+1 in buffer 1
        PHASE(0, 32768,
              { stage_kh(A2g, lds + 0, tid); stage_kh(A2g + 32, lds + 8192, tid); },
              NOGATE);
        PHASE(1, 32768,
              { stage_kh(B3g, lds + 49152, tid); stage_kh(B3g + 32, lds + 57344, tid); },
              NOGATE);
        PHASE(2, 32768, NOSTAGE, NOGATE);
        PHASE(3, 32768, NOSTAGE, VMW(4));
    }
    // tail j=7: tiles 14 (b0), 15 (b1); only stage = T15.A; drain to 0
    {
        const u16* A15 = Ab + 15 * 64;
        PHASE(0, 0,
              { stage_kh(A15, lds + 32768, tid); stage_kh(A15 + 32, lds + 40960, tid); },
              NOGATE);
        PHASE(1, 0, NOSTAGE, NOGATE);
        PHASE(2, 0, NOSTAGE, NOGATE);
        PHASE(3, 0, NOSTAGE, VMW(0));
        PHASE(0, 32768, NOSTAGE, NOGATE);
        PHASE(1, 32768, NOSTAGE, NOGATE);
        PHASE(2, 32768, NOSTAGE, NOGATE);
        PHASE(3, 32768, NOSTAGE, NOGATE);
    }
}

// ---------------- gate GEMM: P = A @ Bcat^T, fused sigmoid-gate epilogue ----
// writes packed ab[row*1024 + ch] = bf16(a) | bf16(b)<<16

__global__ __launch_bounds__(512, 1) void k_gemm_cat8(
    const u16* __restrict__ A, const u16* __restrict__ Bcat,
    const float* __restrict__ gb, const float* __restrict__ ib,
    u32* __restrict__ ab) {
    __shared__ __align__(16) u16 lds[65536];
    const int tid = threadIdx.x, lane = tid & 63;
    const int wm = (tid >> 6) >> 2, wn = (tid >> 6) & 3;

    // bijective XCD swizzle, grid (8, 64) = 512 wg
    int fid = (int)blockIdx.y * 8 + (int)blockIdx.x;
    int swz = (fid & 7) * 64 + (fid >> 3);
    const long bn = swz & 7, bm = swz >> 3;

    f32x4 acc[8][4] = {};
    pipe256(A + bm * 256 * 1024, Bcat + bn * 256 * 1024, lds, acc, tid);

    const long rbase = bm * 256 + wm * 128;
    const int chbase = (int)bn * 128 + wn * 32;
#pragma unroll
    for (int t = 0; t < 2; ++t) {
        int ch = chbase + t * 16 + (lane & 15);
        float g0 = gb[ch], i0 = ib[ch];
#pragma unroll
        for (int m = 0; m < 8; ++m) {
            long row = rbase + m * 16 + ((lane >> 4) << 2);
#pragma unroll
            for (int i = 0; i < 4; ++i) {
                float pg = acc[m][2 * t][i] + g0;
                float pi = acc[m][2 * t + 1][i] + i0;
                float aa = 1.0f / (1.0f + __expf(-pg));
                float bb = (1.0f - aa) * pi;
                ab[(row + i) * 1024 + ch] = (u32)f2bf(aa) | ((u32)f2bf(bb) << 16);
            }
        }
    }
}

// ---------------- final GEMM: out = h @ out_w + x + out_b ----------------

__global__ __launch_bounds__(512, 1) void k_gemm_out8(
    const u16* __restrict__ A, const u16* __restrict__ Bt,
    const float* __restrict__ xres, const float* __restrict__ ob,
    float* __restrict__ out) {
    __shared__ __align__(16) u16 lds[65536];
    const int tid = threadIdx.x, lane = tid & 63;
    const int wm = (tid >> 6) >> 2, wn = (tid >> 6) & 3;

    // bijective XCD swizzle, grid (4, 64) = 256 wg
    int fid = (int)blockIdx.y * 4 + (int)blockIdx.x;
    int swz = (fid & 7) * 32 + (fid >> 3);
    const long bn = swz & 3, bm = swz >> 2;

    f32x4 acc[8][4] = {};
    pipe256(A + bm * 256 * 1024, Bt + bn * 256 * 1024, lds, acc, tid);

    const long rbase = bm * 256 + wm * 128;
    const int cbase = (int)bn * 256 + wn * 64;
#pragma unroll
    for (int n = 0; n < 4; ++n) {
        int col = cbase + n * 16 + (lane & 15);
        float o0 = ob[col];
#pragma unroll
        for (int m = 0; m < 8; ++m) {
            long row = rbase + m * 16 + ((lane >> 4) << 2);
#pragma unroll
            for (int i = 0; i < 4; ++i) {
                long o = (row + i) * 1024 + col;
                out[o] = acc[m][n][i] + o0 + xres[o];
            }
        }
    }
}

// ---------------- conversions ----------------

__global__ __launch_bounds__(256) void k_cvt_x(const float4* __restrict__ x,
                                               uint2* __restrict__ o, int n4) {
    int i = blockIdx.x * 256 + threadIdx.x;
    if (i < n4) {
        float4 v = x[i];
        uint2 r;
        r.x = (u32)f2bf(v.x) | ((u32)f2bf(v.y) << 16);
        r.y = (u32)f2bf(v.z) | ((u32)f2bf(v.w) << 16);
        o[i] = r;
    }
}

__global__ __launch_bounds__(256) void k_transpose_bf(const float* __restrict__ w,
                                                      u16* __restrict__ wt, int R, int C) {
    __shared__ float t[32][33];
    int c0 = blockIdx.x * 32, r0 = blockIdx.y * 32;
    int x = threadIdx.x & 31, y = threadIdx.x >> 5;
    for (int i = y; i < 32; i += 8) t[i][x] = w[(size_t)(r0 + i) * C + c0 + x];
    __syncthreads();
    for (int i = y; i < 32; i += 8) wt[(size_t)(c0 + i) * R + r0 + x] = f2bf(t[x][i]);
}

// Interleaved concat transpose: rows 32t..32t+15 = gate ch 16t..16t+15,
// rows 32t+16..32t+31 = inp, same channels.
__global__ __launch_bounds__(256) void k_transpose_cat(const float* __restrict__ gw,
                                                       const float* __restrict__ iw,
                                                       u16* __restrict__ wt, int K, int C) {
    __shared__ float t[32][33];
    int c0 = blockIdx.x * 32, r0 = blockIdx.y * 32;
    const float* w = blockIdx.z ? iw : gw;
    int x = threadIdx.x & 31, y = threadIdx.x >> 5;
    for (int i = y; i < 32; i += 8) t[i][x] = w[(size_t)(r0 + i) * C + c0 + x];
    __syncthreads();
    for (int i = y; i < 32; i += 8) {
        int ch = c0 + i;
        int r = ((ch >> 4) << 5) | ((int)blockIdx.z << 4) | (ch & 15);
        wt[(size_t)r * K + r0 + x] = f2bf(t[x][i]);
    }
}

// ---------------- chunked affine scan (packed ab stream) ----------------
// ab[row*1024 + ch]: lo = a (bf16), hi = b (bf16). h_t = a*h + b over s.

__global__ __launch_bounds__(256) void k_scanA(const u32* __restrict__ ab,
                                               float2* __restrict__ cAB) {
    int e = blockIdx.x * 256 + threadIdx.x;  // 0..1023
    int c = blockIdx.y, bt = blockIdx.z;
    long base = ((long)bt * 4096 + c * 64) * 1024 + e;
    float Aa = 1.f, H = 0.f;
#pragma unroll 4
    for (int i = 0; i < 64; ++i) {
        u32 v = ab[base + (long)i * 1024];
        float a = bf2f((u16)v), b = bf2f((u16)(v >> 16));
        H = a * H + b;
        Aa *= a;
    }
    cAB[((long)bt * 64 + c) * 1024 + e] = make_float2(Aa, H);
}

__global__ __launch_bounds__(256) void k_scanB(const float2* __restrict__ cAB,
                                               float* __restrict__ hin) {
    int e = blockIdx.x * 256 + threadIdx.x;
    int bt = blockIdx.y;
    float H = 0.f;
#pragma unroll
    for (int c = 0; c < 64; ++c) {
        long s = ((long)bt * 64 + c) * 1024 + e;
        hin[s] = H;
        float2 v = cAB[s];
        H = v.x * H + v.y;
    }
}

__global__ __launch_bounds__(256) void k_scanC(const u32* __restrict__ ab,
                                               const float* __restrict__ hin,
                                               u16* __restrict__ hout) {
    int e = blockIdx.x * 256 + threadIdx.x;
    int c = blockIdx.y, bt = blockIdx.z;
    long base = ((long)bt * 4096 + c * 64) * 1024 + e;
    float H = hin[((long)bt * 64 + c) * 1024 + e];
#pragma unroll 4
    for (int i = 0; i < 64; ++i) {
        u32 v = ab[base + (long)i * 1024];
        H = bf2f((u16)v) * H + bf2f((u16)(v >> 16));
        hout[base + (long)i * 1024] = f2bf(H);
    }
}

// ---------------- launch ----------------

extern "C" void kernel_launch(void* const* d_in, const int* in_sizes, int n_in,
                              void* d_out, int out_size, void* d_ws, size_t ws_size,
                              hipStream_t stream) {
    const float* x      = (const float*)d_in[0];
    const float* gate_w = (const float*)d_in[1];
    const float* gate_b = (const float*)d_in[2];
    const float* inp_w  = (const float*)d_in[3];
    const float* inp_b  = (const float*)d_in[4];
    const float* out_w  = (const float*)d_in[5];
    const float* out_b  = (const float*)d_in[6];
    float* out = (float*)d_out;

    const int Bsz = 4, S = 4096, Din = 1024, Dst = 1024;
    const int M = Bsz * S;                 // 16384
    const long nx = (long)M * Din;         // 16777216

    // workspace layout (bytes)
    char* w = (char*)d_ws;
    u16* xb      = (u16*)(w);                // 33,554,432  x bf16
    u16* catW    = (u16*)(w + 33554432);     //  4,194,304  [gate;inp] interleaved ^T
    u16* owT     = (u16*)(w + 37748736);     //  2,097,152  out_w^T bf16
    u16* hbf     = (u16*)(w + 39845888);     // 33,554,432  scan_out bf16
    float2* cAB  = (float2*)(w + 73400320);  //  2,097,152  chunk (A,H) pairs
    float* hin   = (float*)(w + 75497472);   //  1,048,576  chunk incoming states
    // total 76,546,048 B

    // packed ab lives in d_out (67,108,864 B); overwritten by final GEMM.
    u32* ab = (u32*)d_out;

    // 1. conversions
    k_cvt_x<<<(int)(nx / 4 / 256), 256, 0, stream>>>((const float4*)x, (uint2*)xb, (int)(nx / 4));
    k_transpose_cat<<<dim3(Dst / 32, Din / 32, 2), 256, 0, stream>>>(gate_w, inp_w, catW, Din, Dst);
    k_transpose_bf<<<dim3(Din / 32, Dst / 32), 256, 0, stream>>>(out_w, owT, Dst, Din);

    // 2. fused concat GEMM -> packed ab
    k_gemm_cat8<<<dim3(8, M / 256), 512, 0, stream>>>(xb, catW, gate_b, inp_b, ab);

    // 3. chunked scan -> h (bf16)
    k_scanA<<<dim3(4, 64, Bsz), 256, 0, stream>>>(ab, cAB);
    k_scanB<<<dim3(4, Bsz), 256, 0, stream>>>(cAB, hin);
    k_scanC<<<dim3(4, 64, Bsz), 256, 0, stream>>>(ab, hin, hbf);

    // 4. final GEMM: out = h @ out_w + x + out_b
    k_gemm_out8<<<dim3(4, M / 256), 512, 0, stream>>>(hbf, owT, x, out_b, out);
}